// Round 1
// baseline (141.558 us; speedup 1.0000x reference)
//
#include <hip/hip_runtime.h>

// Problem constants (reference: N=4, L=2048, H=16, D=32, DIM=512)
#define NB      4
#define L_SEQ   2048
#define H_HEADS 16
#define D32     32
#define DIM     512
#define NH      (NB * H_HEADS)   // 64
#define CHUNK   64
#define NCHUNK  (L_SEQ / CHUNK)  // 32

typedef __attribute__((ext_vector_type(8))) short bf16x8;
typedef __attribute__((ext_vector_type(4))) float f32x4;

// f32 -> bf16 round-to-nearest-even (inputs are finite normals)
__device__ __forceinline__ unsigned short f2bf(float x) {
    unsigned u = __float_as_uint(x);
    u += 0x7fff + ((u >> 16) & 1);
    return (unsigned short)(u >> 16);
}
__device__ __forceinline__ unsigned pack2(float lo, float hi) {
    return (unsigned)f2bf(lo) | ((unsigned)f2bf(hi) << 16);
}

// ---------------------------------------------------------------------------
// Kernel 0: f32 -> bf16 conversion of query, key, Wq, Wk, Wv into one
// contiguous bf16 region (same order). 8 elements/thread, exact cover.
// ---------------------------------------------------------------------------
#define QN  4194304           // query elems
#define WN  262144            // one weight matrix
#define TOT (2*QN + 3*WN)     // 9,175,040
__global__ __launch_bounds__(256) void convert_kernel(
    const float* __restrict__ query, const float* __restrict__ key,
    const float* __restrict__ Wq, const float* __restrict__ Wk,
    const float* __restrict__ Wv, unsigned short* __restrict__ dst)
{
    int idx = (blockIdx.x * 256 + threadIdx.x) * 8;
    const float* src; int off;
    if (idx < QN)               { src = query; off = idx; }
    else if (idx < 2*QN)        { src = key;   off = idx - QN; }
    else if (idx < 2*QN + WN)   { src = Wq;    off = idx - 2*QN; }
    else if (idx < 2*QN + 2*WN) { src = Wk;    off = idx - 2*QN - WN; }
    else                        { src = Wv;    off = idx - 2*QN - 2*WN; }
    float4 a = *(const float4*)(src + off);
    float4 b = *(const float4*)(src + off + 4);
    *(uint4*)(dst + idx) = make_uint4(pack2(a.x, a.y), pack2(a.z, a.w),
                                      pack2(b.x, b.y), pack2(b.z, b.w));
}

// ---------------------------------------------------------------------------
// Kernel 1: three GEMMs via bf16 MFMA, fused over blockIdx.z.
//   z=0: C[l][dout] = query @ Wq^T -> softmax(heads) -> Qs [nh][l][d]
//   z=1: C[l][dout] = key   @ Wk^T -> softmax(heads) -> Ks [nh][l][d]
//   z=2: C[dout][l] = Wv @ key^T   -> Vt [nh][d][l]   (transposed compute)
// Grid (256,1,3) with XCD swizzle: bx = lin>>6 (col-tile), by = lin&63
// (row-tile). The 4 blocks sharing an A-stripe are 64 apart in dispatch
// order (64 % 8 == 0) -> same XCD -> A re-reads hit that XCD's L2.
//
// This round: T3 minimal 2-phase pipeline.
//  - global_load_lds width-16 staging (no VGPR round-trip)
//  - double-buffered LDS, stage(next) issued BEFORE compute(cur),
//    ONE barrier per K-step -> load latency hidden under MFMAs
//  - involution XOR swizzle (q' = q ^ ((row>>1)&3), bits4-5 ^ bits7-8)
//    folded into the GLOBAL source address (linear LDS dest, rule #21)
//    and applied on the ds_read side: kills the 8-way bank conflict of
//    64B-row tiles (1.57M conflicts/dispatch -> ~0).
// ---------------------------------------------------------------------------
#define GLL(g, l) __builtin_amdgcn_global_load_lds( \
    (const __attribute__((address_space(1))) unsigned int*)(g), \
    (__attribute__((address_space(3))) unsigned int*)(l), 16, 0, 0)

__global__ __launch_bounds__(256) void gemm3_mfma_kernel(
    const unsigned short* __restrict__ qb, const unsigned short* __restrict__ kb2,
    const unsigned short* __restrict__ wqb, const unsigned short* __restrict__ wkb,
    const unsigned short* __restrict__ wvb,
    unsigned short* __restrict__ Qs, unsigned short* __restrict__ Ks,
    unsigned short* __restrict__ Vt)
{
    const int z  = blockIdx.z;
    const int bx = blockIdx.x >> 6;      // 0..3  (128-col tile)
    const int by = blockIdx.x & 63;      // 0..63 (128-row tile)
    const unsigned short *PA, *PB;   // PA rows = output rows(m), PB rows = cols(n)
    int m0, n0;
    if (z == 0)      { PA = qb;  PB = wqb; m0 = by*128; n0 = bx*128; }
    else if (z == 1) { PA = kb2; PB = wkb; m0 = by*128; n0 = bx*128; }
    else             { PA = wvb; PB = kb2; m0 = bx*128; n0 = by*128; }

    __shared__ unsigned short Asm[2 * 4096];   // 2 x 8 KB (128x32 bf16)
    __shared__ unsigned short Bsm[2 * 4096];   // 2 x 8 KB

    const int t    = threadIdx.x;
    const int w    = t >> 6;
    const int lane = t & 63;
    const int wm   = w >> 1, wn = w & 1;
    const int lm   = lane & 15, quad = lane >> 4;

    // ds_read side of the involution swizzle: row base is a multiple of 16,
    // so (row>>1)&3 == (lm>>1)&3 for every fragment row this lane touches.
    const int qswz = quad ^ ((lm >> 1) & 3);
    const int aoff = (wm * 64 + lm) * 32 + qswz * 8;   // + i*512 per tile
    const int boff = (wn * 64 + lm) * 32 + qswz * 8;   // + j*512 per tile

    // Staging geometry: chunk li covers LDS bytes [li*16, li*16+16).
    // Linear LDS dest (global_load_lds requirement); the swizzle is applied
    // by permuting which global 16B block each lane fetches:
    //   logical slot = P(li*16), P = XOR bits4-5 with bits7-8 (involution)
    //   -> row = li>>2 (unchanged), q_src = (li&3) ^ ((li>>3)&3)
    const int li0 = t, li1 = t + 256;
    const int row0 = li0 >> 2, row1 = li1 >> 2;
    const int qs0 = (li0 & 3) ^ ((li0 >> 3) & 3);
    const int qs1 = (li1 & 3) ^ ((li1 >> 3) & 3);
    const unsigned short* gA0 = PA + (size_t)(m0 + row0) * DIM + qs0 * 8;
    const unsigned short* gA1 = PA + (size_t)(m0 + row1) * DIM + qs1 * 8;
    const unsigned short* gB0 = PB + (size_t)(n0 + row0) * DIM + qs0 * 8;
    const unsigned short* gB1 = PB + (size_t)(n0 + row1) * DIM + qs1 * 8;

    f32x4 acc[4][4] = {};

#define STAGE(buf, kb) do { \
    GLL(gA0 + (kb), Asm + (buf) * 4096 + li0 * 8); \
    GLL(gB0 + (kb), Bsm + (buf) * 4096 + li0 * 8); \
    GLL(gA1 + (kb), Asm + (buf) * 4096 + li1 * 8); \
    GLL(gB1 + (kb), Bsm + (buf) * 4096 + li1 * 8); \
} while (0)

    STAGE(0, 0);
    __syncthreads();                       // drains vmcnt(0): buf0 ready

    #pragma unroll
    for (int step = 0; step < 16; ++step) {
        const int cur = step & 1;
        if (step < 15) STAGE(cur ^ 1, (step + 1) * 32);   // prefetch next tile
        const unsigned short* As = Asm + cur * 4096;
        const unsigned short* Bs = Bsm + cur * 4096;
        bf16x8 af[4], bfr[4];
        #pragma unroll
        for (int i = 0; i < 4; i++)
            af[i] = *(const bf16x8*)(As + aoff + i * 512);
        #pragma unroll
        for (int j = 0; j < 4; j++)
            bfr[j] = *(const bf16x8*)(Bs + boff + j * 512);
        #pragma unroll
        for (int i = 0; i < 4; i++)
            #pragma unroll
            for (int j = 0; j < 4; j++)
                acc[i][j] = __builtin_amdgcn_mfma_f32_16x16x32_bf16(
                    af[i], bfr[j], acc[i][j], 0, 0, 0);
        // one barrier per K-step: orders compute(cur) reads before next
        // stage's writes to buf cur, and drains the prefetch (vmcnt(0))
        // AFTER this step's MFMAs instead of before them.
        if (step < 15) __syncthreads();
    }
#undef STAGE

    // fused softmax over D=32 head groups along cols (Q and K only)
    if (z < 2) {
        #pragma unroll
        for (int i = 0; i < 4; i++)
            #pragma unroll
            for (int jp = 0; jp < 2; jp++)
                #pragma unroll
                for (int r = 0; r < 4; r++) {
                    float a = acc[i][2 * jp][r], b = acc[i][2 * jp + 1][r];
                    float m = fmaxf(a, b);
                    #pragma unroll
                    for (int off = 1; off < 16; off <<= 1)
                        m = fmaxf(m, __shfl_xor(m, off, 64));
                    float ea = __expf(a - m), eb = __expf(b - m);
                    float s = ea + eb;
                    #pragma unroll
                    for (int off = 1; off < 16; off <<= 1)
                        s += __shfl_xor(s, off, 64);
                    float inv = 1.0f / s;
                    acc[i][2 * jp][r]     = ea * inv;
                    acc[i][2 * jp + 1][r] = eb * inv;
                }
    }

    // epilogue: C frag row = m0+wm*64+i*16+quad*4+r, col = n0+wn*64+j*16+lm
    #pragma unroll
    for (int i = 0; i < 4; i++) {
        int rbase = m0 + wm * 64 + i * 16 + quad * 4;
        #pragma unroll
        for (int r = 0; r < 4; r++) {
            int rg = rbase + r;
            #pragma unroll
            for (int j = 0; j < 4; j++) {
                int cg = n0 + wn * 64 + j * 16 + lm;
                unsigned short val = f2bf(acc[i][j][r]);
                if (z < 2) {
                    int n = rg >> 11, l = rg & 2047;
                    int h = cg >> 5,  e = cg & 31;
                    unsigned short* dp = (z == 0) ? Qs : Ks;
                    dp[(((size_t)(n * H_HEADS + h)) * L_SEQ + l) * D32 + e] = val;
                } else {
                    int h = rg >> 5,  e = rg & 31;     // rows are dout
                    int n = cg >> 11, l = cg & 2047;   // cols are l
                    Vt[(((size_t)(n * H_HEADS + h)) * D32 + e) * L_SEQ + l] = val;
                }
            }
        }
    }
}

// ---------------------------------------------------------------------------
// Kernel 2: per-chunk KV sums via MFMA — ONE WAVE PER CHUNK (64-thr blocks).
//   ckvT[e][d] = sum_l V[l][e] * K[l][d]
// Wave stages its chunk's K into a private LDS transpose buffer (stride 36),
// then 8 MFMAs. No inter-wave coupling; 2048 blocks.
// ---------------------------------------------------------------------------
__global__ __launch_bounds__(64) void chunk_kv_mfma_kernel(
    const unsigned short* __restrict__ Ks, const unsigned short* __restrict__ Vt,
    float* __restrict__ ckvT)
{
    const int c = blockIdx.x, nh = blockIdx.y;
    const int lane = threadIdx.x;
    const int lm = lane & 15, quad = lane >> 4;

    __shared__ unsigned short Kl[64 * 36];   // 4.5 KB

    // stage: lane loads its row (64B contiguous) -> padded LDS row
    {
        const unsigned short* kg = Ks + ((size_t)nh * L_SEQ + c * CHUNK + lane) * D32;
        #pragma unroll
        for (int i = 0; i < 4; i++) {
            uint4 v = *(const uint4*)(kg + i * 8);
            *(uint4*)(Kl + lane * 36 + i * 8) = v;
        }
    }
    __syncthreads();   // single wave: cheap; orders LDS writes before reads

    f32x4 acc[2][2] = {};
    #pragma unroll
    for (int ch = 0; ch < 2; ch++) {
        bf16x8 aV[2], bK[2];
        #pragma unroll
        for (int mt = 0; mt < 2; mt++)
            aV[mt] = *(const bf16x8*)(Vt + ((size_t)nh * D32 + mt * 16 + lm) * L_SEQ
                                         + c * CHUNK + ch * 32 + quad * 8);
        #pragma unroll
        for (int nt = 0; nt < 2; nt++) {
            const unsigned short* kp = Kl + (ch * 32 + quad * 8) * 36 + nt * 16 + lm;
            #pragma unroll
            for (int j = 0; j < 8; j++) bK[nt][j] = (short)kp[j * 36];
        }
        #pragma unroll
        for (int mt = 0; mt < 2; mt++)
            #pragma unroll
            for (int nt = 0; nt < 2; nt++)
                acc[mt][nt] = __builtin_amdgcn_mfma_f32_16x16x32_bf16(
                    aV[mt], bK[nt], acc[mt][nt], 0, 0, 0);
    }
    #pragma unroll
    for (int mt = 0; mt < 2; mt++)
        #pragma unroll
        for (int nt = 0; nt < 2; nt++)
            #pragma unroll
            for (int r = 0; r < 4; r++) {
                int e = mt * 16 + quad * 4 + r;
                int d = nt * 16 + lm;
                ckvT[(((size_t)nh * NCHUNK + c) * 32 + e) * 32 + d] = acc[mt][nt][r];
            }
}

// ---------------------------------------------------------------------------
// Kernel 3: exclusive prefix over 32 chunks; reads ckvT f32, writes SpT bf16.
// Grid (4, NH), 64 threads: block handles 64 of the 256 float4 slots.
// ---------------------------------------------------------------------------
__global__ __launch_bounds__(64) void prefix_kernel(
    const float* __restrict__ ckvT, unsigned short* __restrict__ SpT)
{
    int nh   = blockIdx.y;
    int slot = blockIdx.x * 64 + threadIdx.x;   // 0..255
    const float* base = ckvT + (size_t)nh * NCHUNK * 1024 + slot * 4;
    unsigned short* sp = SpT + (size_t)nh * NCHUNK * 1024 + slot * 4;
    float4 acc = make_float4(0.f, 0.f, 0.f, 0.f);
    #pragma unroll
    for (int cb = 0; cb < NCHUNK; cb += 8) {
        float4 v[8];
        #pragma unroll
        for (int j = 0; j < 8; j++)
            v[j] = *(const float4*)(base + (size_t)(cb + j) * 1024);
        #pragma unroll
        for (int j = 0; j < 8; j++) {
            ushort4 u;
            u.x = f2bf(acc.x); u.y = f2bf(acc.y);
            u.z = f2bf(acc.z); u.w = f2bf(acc.w);
            *(ushort4*)(sp + (size_t)(cb + j) * 1024) = u;
            acc.x += v[j].x; acc.y += v[j].y;
            acc.z += v[j].z; acc.w += v[j].w;
        }
    }
}

// ---------------------------------------------------------------------------
// Kernel 4: per-chunk output via MFMA — ONE WAVE PER CHUNK (64-thr blocks).
//   P = tril(Qc Kc^T) (bf16, private LDS);  O = Qc·SpT^T + P·Vt^T
// Wave owns all 4 row-tiles: 10 + 20 MFMAs, ~14 vector frag loads -> high ILP.
// ---------------------------------------------------------------------------
__global__ __launch_bounds__(64) void chunk_out_mfma_kernel(
    const unsigned short* __restrict__ Qs, const unsigned short* __restrict__ Ks,
    const unsigned short* __restrict__ Vt, const unsigned short* __restrict__ SpT,
    float* __restrict__ out)
{
    const int c = blockIdx.x, nh = blockIdx.y;
    __shared__ unsigned short P[64 * 72];   // row l, col l', stride 72 (9 KB)

    const int lane = threadIdx.x;
    const int lm = lane & 15, quad = lane >> 4;

    // A-frags of Q and B-frags of K for all 4 tiles
    bf16x8 aQ[4], bK[4];
    #pragma unroll
    for (int i = 0; i < 4; i++)
        aQ[i] = *(const bf16x8*)(Qs + ((size_t)nh * L_SEQ + c * CHUNK + i * 16 + lm) * D32
                                    + quad * 8);
    #pragma unroll
    for (int j = 0; j < 4; j++)
        bK[j] = *(const bf16x8*)(Ks + ((size_t)nh * L_SEQ + c * CHUNK + j * 16 + lm) * D32
                                    + quad * 8);

    // Phase A: P[i][j] tiles; upper (j>i) zero-filled
    #pragma unroll
    for (int i = 0; i < 4; i++) {
        #pragma unroll
        for (int j = 0; j < 4; j++) {
            f32x4 p = {};
            if (j <= i) {
                p = __builtin_amdgcn_mfma_f32_16x16x32_bf16(aQ[i], bK[j], p, 0, 0, 0);
                if (j == i) {
                    #pragma unroll
                    for (int r = 0; r < 4; r++)
                        if (lm > quad * 4 + r) p[r] = 0.f;   // causal: keep l' <= l
                }
            }
            #pragma unroll
            for (int r = 0; r < 4; r++)
                P[(i * 16 + quad * 4 + r) * 72 + j * 16 + lm] = f2bf(p[r]);
        }
    }
    __syncthreads();   // single wave: orders LDS writes before reads

    // preload phase-B global frags
    bf16x8 bS[2], bV[2][2];
    #pragma unroll
    for (int nt = 0; nt < 2; nt++) {
        bS[nt] = *(const bf16x8*)(SpT + (((size_t)nh * NCHUNK + c) * 32 + nt * 16 + lm) * 32
                                      + quad * 8);
        #pragma unroll
        for (int ch = 0; ch < 2; ch++)
            bV[nt][ch] = *(const bf16x8*)(Vt + ((size_t)nh * D32 + nt * 16 + lm) * L_SEQ
                                             + c * CHUNK + ch * 32 + quad * 8);
    }

    const int n = nh >> 4, h = nh & 15;
    #pragma unroll
    for (int i = 0; i < 4; i++) {
        const int chmax = (i >> 1) + 1;   // tiles of lp needed: i<2 -> 1, else 2
        bf16x8 aP[2];
        for (int ch = 0; ch < chmax; ch++)
            aP[ch] = *(const bf16x8*)&P[(i * 16 + lm) * 72 + ch * 32 + quad * 8];
        #pragma unroll
        for (int nt = 0; nt < 2; nt++) {
            f32x4 acc = {};
            acc = __builtin_amdgcn_mfma_f32_16x16x32_bf16(aQ[i], bS[nt], acc, 0, 0, 0);
            for (int ch = 0; ch < chmax; ch++)
                acc = __builtin_amdgcn_mfma_f32_16x16x32_bf16(aP[ch], bV[nt][ch], acc, 0, 0, 0);
            #pragma unroll
            for (int r = 0; r < 4; r++) {
                int lg = c * CHUNK + i * 16 + quad * 4 + r;
                out[((size_t)n * L_SEQ + lg) * DIM + h * D32 + nt * 16 + lm] = acc[r];
            }
        }
    }
}

// ---------------------------------------------------------------------------
extern "C" void kernel_launch(void* const* d_in, const int* in_sizes, int n_in,
                              void* d_out, int out_size, void* d_ws, size_t ws_size,
                              hipStream_t stream)
{
    (void)in_sizes; (void)n_in; (void)out_size; (void)ws_size;
    const float* query = (const float*)d_in[0];
    const float* key   = (const float*)d_in[1];
    const float* Wq    = (const float*)d_in[2];
    const float* Wk    = (const float*)d_in[3];
    const float* Wv    = (const float*)d_in[4];
    float* out = (float*)d_out;

    // ws layout (bf16 shorts unless noted):
    //  [qb 4.19M][kb 4.19M][wqb 256K][wkb 256K][wvb 256K]
    //  [Qs 4.19M][Ks 4.19M][Vt 4.19M][SpT 2.10M][ckvT f32 2.10M]  ~= 56 MB
    unsigned short* bf = (unsigned short*)d_ws;
    unsigned short* qb  = bf;
    unsigned short* kb  = qb + QN;
    unsigned short* wqb = kb + QN;
    unsigned short* wkb = wqb + WN;
    unsigned short* wvb = wkb + WN;
    unsigned short* Qs  = wvb + WN;
    const size_t SZ = (size_t)NH * L_SEQ * D32;
    unsigned short* Ks  = Qs + SZ;
    unsigned short* Vt  = Ks + SZ;
    unsigned short* SpT = Vt + SZ;
    float* ckvT = (float*)(SpT + (size_t)NH * NCHUNK * 1024);

    convert_kernel<<<dim3(TOT / (256 * 8)), dim3(256), 0, stream>>>(
        query, key, Wq, Wk, Wv, qb);
    gemm3_mfma_kernel<<<dim3(256, 1, 3), dim3(256), 0, stream>>>(
        qb, kb, wqb, wkb, wvb, Qs, Ks, Vt);
    chunk_kv_mfma_kernel<<<dim3(NCHUNK, NH), dim3(64), 0, stream>>>(Ks, Vt, ckvT);
    prefix_kernel<<<dim3(4, NH), dim3(64), 0, stream>>>(ckvT, SpT);
    chunk_out_mfma_kernel<<<dim3(NCHUNK, NH), dim3(64), 0, stream>>>(Qs, Ks, Vt, SpT, out);
}

// Round 2
// 138.289 us; speedup vs baseline: 1.0236x; 1.0236x over previous
//
#include <hip/hip_runtime.h>

// Problem constants (reference: N=4, L=2048, H=16, D=32, DIM=512)
#define NB      4
#define L_SEQ   2048
#define H_HEADS 16
#define D32     32
#define DIM     512
#define NH      (NB * H_HEADS)   // 64
#define CHUNK   64
#define NCHUNK  (L_SEQ / CHUNK)  // 32

typedef __attribute__((ext_vector_type(8))) short bf16x8;
typedef __attribute__((ext_vector_type(4))) float f32x4;

// f32 -> bf16 round-to-nearest-even (inputs are finite normals)
__device__ __forceinline__ unsigned short f2bf(float x) {
    unsigned u = __float_as_uint(x);
    u += 0x7fff + ((u >> 16) & 1);
    return (unsigned short)(u >> 16);
}
__device__ __forceinline__ unsigned pack2(float lo, float hi) {
    return (unsigned)f2bf(lo) | ((unsigned)f2bf(hi) << 16);
}

// ---------------------------------------------------------------------------
// Kernel 0: f32 -> bf16 conversion of query, key, Wq, Wk, Wv into one
// contiguous bf16 region (same order). 8 elements/thread, exact cover.
// ---------------------------------------------------------------------------
#define QN  4194304           // query elems
#define WN  262144            // one weight matrix
#define TOT (2*QN + 3*WN)     // 9,175,040
__global__ __launch_bounds__(256) void convert_kernel(
    const float* __restrict__ query, const float* __restrict__ key,
    const float* __restrict__ Wq, const float* __restrict__ Wk,
    const float* __restrict__ Wv, unsigned short* __restrict__ dst)
{
    int idx = (blockIdx.x * 256 + threadIdx.x) * 8;
    const float* src; int off;
    if (idx < QN)               { src = query; off = idx; }
    else if (idx < 2*QN)        { src = key;   off = idx - QN; }
    else if (idx < 2*QN + WN)   { src = Wq;    off = idx - 2*QN; }
    else if (idx < 2*QN + 2*WN) { src = Wk;    off = idx - 2*QN - WN; }
    else                        { src = Wv;    off = idx - 2*QN - 2*WN; }
    float4 a = *(const float4*)(src + off);
    float4 b = *(const float4*)(src + off + 4);
    *(uint4*)(dst + idx) = make_uint4(pack2(a.x, a.y), pack2(a.z, a.w),
                                      pack2(b.x, b.y), pack2(b.z, b.w));
}

// ---------------------------------------------------------------------------
// Kernel 1: three GEMMs via bf16 MFMA, fused over blockIdx.z.
//   z=0: C[l][dout] = query @ Wq^T -> softmax(heads) -> Qs [nh][l][d]
//   z=1: C[l][dout] = key   @ Wk^T -> softmax(heads) -> Ks [nh][l][d]
//   z=2: C[dout][l] = Wv @ key^T   -> Vt [nh][d][l]   (transposed compute)
// Grid (256,1,3) with XCD swizzle: bx = lin>>6 (col-tile), by = lin&63.
//
// Round 2: distance-2 pipeline with COUNTED vmcnt (T3+T4).
//   Round-1 post-mortem: distance-1 + __syncthreads gave 0 gain because
//   __syncthreads drains vmcnt(0) -> the just-issued prefetch must fully
//   land every step (the "m97 ceiling" failure). Now: 3 LDS buffers,
//   prefetch distance 2, raw s_barrier + s_waitcnt vmcnt(4) so the newest
//   stage's 4 loads stay in flight across the barrier. Each load gets ~2
//   full steps to complete -> per-step cost ~= compute + barrier.
//   Safety: buffer b[(t+2)%3] staged at step t was last read at step t-1;
//   every wave's ds_reads complete before its barrier arrival (compiler
//   lgkmcnt wait precedes the MFMAs, sched_barrier(0) pins MFMAs before
//   the barrier), so the overwrite is race-free. Per-wave vmcnt covers
//   that wave's own LDS writes; barrier publishes them to the block.
// ---------------------------------------------------------------------------
#define GLL(g, l) __builtin_amdgcn_global_load_lds( \
    (const __attribute__((address_space(1))) unsigned int*)(g), \
    (__attribute__((address_space(3))) unsigned int*)(l), 16, 0, 0)

__global__ __launch_bounds__(256) void gemm3_mfma_kernel(
    const unsigned short* __restrict__ qb, const unsigned short* __restrict__ kb2,
    const unsigned short* __restrict__ wqb, const unsigned short* __restrict__ wkb,
    const unsigned short* __restrict__ wvb,
    unsigned short* __restrict__ Qs, unsigned short* __restrict__ Ks,
    unsigned short* __restrict__ Vt)
{
    const int z  = blockIdx.z;
    const int bx = blockIdx.x >> 6;      // 0..3  (128-col tile)
    const int by = blockIdx.x & 63;      // 0..63 (128-row tile)
    const unsigned short *PA, *PB;   // PA rows = output rows(m), PB rows = cols(n)
    int m0, n0;
    if (z == 0)      { PA = qb;  PB = wqb; m0 = by*128; n0 = bx*128; }
    else if (z == 1) { PA = kb2; PB = wkb; m0 = by*128; n0 = bx*128; }
    else             { PA = wvb; PB = kb2; m0 = bx*128; n0 = by*128; }

    __shared__ unsigned short Asm[3 * 4096];   // 3 x 8 KB (128x32 bf16)
    __shared__ unsigned short Bsm[3 * 4096];   // 3 x 8 KB

    const int t    = threadIdx.x;
    const int w    = t >> 6;
    const int lane = t & 63;
    const int wm   = w >> 1, wn = w & 1;
    const int lm   = lane & 15, quad = lane >> 4;

    // ds_read side of the involution swizzle: row base is a multiple of 16,
    // so (row>>1)&3 == (lm>>1)&3 for every fragment row this lane touches.
    const int qswz = quad ^ ((lm >> 1) & 3);
    const int aoff = (wm * 64 + lm) * 32 + qswz * 8;   // + i*512 per tile
    const int boff = (wn * 64 + lm) * 32 + qswz * 8;   // + j*512 per tile

    // Staging geometry: chunk li covers LDS bytes [li*16, li*16+16).
    // Linear LDS dest (global_load_lds requirement); the swizzle is applied
    // by permuting which global 16B block each lane fetches:
    //   row = li>>2 (unchanged), q_src = (li&3) ^ ((li>>3)&3)  (involution)
    const int li0 = t, li1 = t + 256;
    const int row0 = li0 >> 2, row1 = li1 >> 2;
    const int qs0 = (li0 & 3) ^ ((li0 >> 3) & 3);
    const int qs1 = (li1 & 3) ^ ((li1 >> 3) & 3);
    const unsigned short* gA0 = PA + (size_t)(m0 + row0) * DIM + qs0 * 8;
    const unsigned short* gA1 = PA + (size_t)(m0 + row1) * DIM + qs1 * 8;
    const unsigned short* gB0 = PB + (size_t)(n0 + row0) * DIM + qs0 * 8;
    const unsigned short* gB1 = PB + (size_t)(n0 + row1) * DIM + qs1 * 8;

    f32x4 acc[4][4] = {};

#define STAGE(buf, kb) do { \
    GLL(gA0 + (kb), Asm + (buf) * 4096 + li0 * 8); \
    GLL(gB0 + (kb), Bsm + (buf) * 4096 + li0 * 8); \
    GLL(gA1 + (kb), Asm + (buf) * 4096 + li1 * 8); \
    GLL(gB1 + (kb), Bsm + (buf) * 4096 + li1 * 8); \
} while (0)

    // prologue: fill buf0 and buf1 (8 loads/wave), wait only for buf0
    STAGE(0, 0);
    STAGE(1, 32);
    __builtin_amdgcn_sched_barrier(0);
    asm volatile("s_waitcnt vmcnt(4)" ::: "memory");
    __builtin_amdgcn_s_barrier();
    __builtin_amdgcn_sched_barrier(0);

    #pragma unroll
    for (int step = 0; step < 16; ++step) {
        const int cur = step % 3;
        if (step < 14) STAGE((step + 2) % 3, (step + 2) * 32);  // distance-2
        const unsigned short* As = Asm + cur * 4096;
        const unsigned short* Bs = Bsm + cur * 4096;
        bf16x8 af[4], bfr[4];
        #pragma unroll
        for (int i = 0; i < 4; i++)
            af[i] = *(const bf16x8*)(As + aoff + i * 512);
        #pragma unroll
        for (int j = 0; j < 4; j++)
            bfr[j] = *(const bf16x8*)(Bs + boff + j * 512);
        #pragma unroll
        for (int i = 0; i < 4; i++)
            #pragma unroll
            for (int j = 0; j < 4; j++)
                acc[i][j] = __builtin_amdgcn_mfma_f32_16x16x32_bf16(
                    af[i], bfr[j], acc[i][j], 0, 0, 0);
        // counted wait: only the OLDER stage (next step's buffer) must have
        // landed; the 4 loads issued this step stay in flight across the
        // barrier. Never vmcnt(0) in the main loop.
        __builtin_amdgcn_sched_barrier(0);
        if (step < 14)       asm volatile("s_waitcnt vmcnt(4)" ::: "memory");
        else if (step == 14) asm volatile("s_waitcnt vmcnt(0)" ::: "memory");
        if (step < 15) {
            __builtin_amdgcn_s_barrier();
            __builtin_amdgcn_sched_barrier(0);
        }
    }
#undef STAGE

    // fused softmax over D=32 head groups along cols (Q and K only)
    if (z < 2) {
        #pragma unroll
        for (int i = 0; i < 4; i++)
            #pragma unroll
            for (int jp = 0; jp < 2; jp++)
                #pragma unroll
                for (int r = 0; r < 4; r++) {
                    float a = acc[i][2 * jp][r], b = acc[i][2 * jp + 1][r];
                    float m = fmaxf(a, b);
                    #pragma unroll
                    for (int off = 1; off < 16; off <<= 1)
                        m = fmaxf(m, __shfl_xor(m, off, 64));
                    float ea = __expf(a - m), eb = __expf(b - m);
                    float s = ea + eb;
                    #pragma unroll
                    for (int off = 1; off < 16; off <<= 1)
                        s += __shfl_xor(s, off, 64);
                    float inv = 1.0f / s;
                    acc[i][2 * jp][r]     = ea * inv;
                    acc[i][2 * jp + 1][r] = eb * inv;
                }
    }

    // epilogue: C frag row = m0+wm*64+i*16+quad*4+r, col = n0+wn*64+j*16+lm
    #pragma unroll
    for (int i = 0; i < 4; i++) {
        int rbase = m0 + wm * 64 + i * 16 + quad * 4;
        #pragma unroll
        for (int r = 0; r < 4; r++) {
            int rg = rbase + r;
            #pragma unroll
            for (int j = 0; j < 4; j++) {
                int cg = n0 + wn * 64 + j * 16 + lm;
                unsigned short val = f2bf(acc[i][j][r]);
                if (z < 2) {
                    int n = rg >> 11, l = rg & 2047;
                    int h = cg >> 5,  e = cg & 31;
                    unsigned short* dp = (z == 0) ? Qs : Ks;
                    dp[(((size_t)(n * H_HEADS + h)) * L_SEQ + l) * D32 + e] = val;
                } else {
                    int h = rg >> 5,  e = rg & 31;     // rows are dout
                    int n = cg >> 11, l = cg & 2047;   // cols are l
                    Vt[(((size_t)(n * H_HEADS + h)) * D32 + e) * L_SEQ + l] = val;
                }
            }
        }
    }
}

// ---------------------------------------------------------------------------
// Kernel 2: per-chunk KV sums via MFMA — ONE WAVE PER CHUNK (64-thr blocks).
//   ckvT[e][d] = sum_l V[l][e] * K[l][d]
// Wave stages its chunk's K into a private LDS transpose buffer (stride 36),
// then 8 MFMAs. No inter-wave coupling; 2048 blocks.
// ---------------------------------------------------------------------------
__global__ __launch_bounds__(64) void chunk_kv_mfma_kernel(
    const unsigned short* __restrict__ Ks, const unsigned short* __restrict__ Vt,
    float* __restrict__ ckvT)
{
    const int c = blockIdx.x, nh = blockIdx.y;
    const int lane = threadIdx.x;
    const int lm = lane & 15, quad = lane >> 4;

    __shared__ unsigned short Kl[64 * 36];   // 4.5 KB

    // stage: lane loads its row (64B contiguous) -> padded LDS row
    {
        const unsigned short* kg = Ks + ((size_t)nh * L_SEQ + c * CHUNK + lane) * D32;
        #pragma unroll
        for (int i = 0; i < 4; i++) {
            uint4 v = *(const uint4*)(kg + i * 8);
            *(uint4*)(Kl + lane * 36 + i * 8) = v;
        }
    }
    __syncthreads();   // single wave: cheap; orders LDS writes before reads

    f32x4 acc[2][2] = {};
    #pragma unroll
    for (int ch = 0; ch < 2; ch++) {
        bf16x8 aV[2], bK[2];
        #pragma unroll
        for (int mt = 0; mt < 2; mt++)
            aV[mt] = *(const bf16x8*)(Vt + ((size_t)nh * D32 + mt * 16 + lm) * L_SEQ
                                         + c * CHUNK + ch * 32 + quad * 8);
        #pragma unroll
        for (int nt = 0; nt < 2; nt++) {
            const unsigned short* kp = Kl + (ch * 32 + quad * 8) * 36 + nt * 16 + lm;
            #pragma unroll
            for (int j = 0; j < 8; j++) bK[nt][j] = (short)kp[j * 36];
        }
        #pragma unroll
        for (int mt = 0; mt < 2; mt++)
            #pragma unroll
            for (int nt = 0; nt < 2; nt++)
                acc[mt][nt] = __builtin_amdgcn_mfma_f32_16x16x32_bf16(
                    aV[mt], bK[nt], acc[mt][nt], 0, 0, 0);
    }
    #pragma unroll
    for (int mt = 0; mt < 2; mt++)
        #pragma unroll
        for (int nt = 0; nt < 2; nt++)
            #pragma unroll
            for (int r = 0; r < 4; r++) {
                int e = mt * 16 + quad * 4 + r;
                int d = nt * 16 + lm;
                ckvT[(((size_t)nh * NCHUNK + c) * 32 + e) * 32 + d] = acc[mt][nt][r];
            }
}

// ---------------------------------------------------------------------------
// Kernel 3: exclusive prefix over 32 chunks; reads ckvT f32, writes SpT bf16.
// Grid (4, NH), 64 threads: block handles 64 of the 256 float4 slots.
// ---------------------------------------------------------------------------
__global__ __launch_bounds__(64) void prefix_kernel(
    const float* __restrict__ ckvT, unsigned short* __restrict__ SpT)
{
    int nh   = blockIdx.y;
    int slot = blockIdx.x * 64 + threadIdx.x;   // 0..255
    const float* base = ckvT + (size_t)nh * NCHUNK * 1024 + slot * 4;
    unsigned short* sp = SpT + (size_t)nh * NCHUNK * 1024 + slot * 4;
    float4 acc = make_float4(0.f, 0.f, 0.f, 0.f);
    #pragma unroll
    for (int cb = 0; cb < NCHUNK; cb += 8) {
        float4 v[8];
        #pragma unroll
        for (int j = 0; j < 8; j++)
            v[j] = *(const float4*)(base + (size_t)(cb + j) * 1024);
        #pragma unroll
        for (int j = 0; j < 8; j++) {
            ushort4 u;
            u.x = f2bf(acc.x); u.y = f2bf(acc.y);
            u.z = f2bf(acc.z); u.w = f2bf(acc.w);
            *(ushort4*)(sp + (size_t)(cb + j) * 1024) = u;
            acc.x += v[j].x; acc.y += v[j].y;
            acc.z += v[j].z; acc.w += v[j].w;
        }
    }
}

// ---------------------------------------------------------------------------
// Kernel 4: per-chunk output via MFMA — ONE WAVE PER CHUNK (64-thr blocks).
//   P = tril(Qc Kc^T) (bf16, private LDS);  O = Qc·SpT^T + P·Vt^T
// Wave owns all 4 row-tiles: 10 + 20 MFMAs, ~14 vector frag loads -> high ILP.
// ---------------------------------------------------------------------------
__global__ __launch_bounds__(64) void chunk_out_mfma_kernel(
    const unsigned short* __restrict__ Qs, const unsigned short* __restrict__ Ks,
    const unsigned short* __restrict__ Vt, const unsigned short* __restrict__ SpT,
    float* __restrict__ out)
{
    const int c = blockIdx.x, nh = blockIdx.y;
    __shared__ unsigned short P[64 * 72];   // row l, col l', stride 72 (9 KB)

    const int lane = threadIdx.x;
    const int lm = lane & 15, quad = lane >> 4;

    // A-frags of Q and B-frags of K for all 4 tiles
    bf16x8 aQ[4], bK[4];
    #pragma unroll
    for (int i = 0; i < 4; i++)
        aQ[i] = *(const bf16x8*)(Qs + ((size_t)nh * L_SEQ + c * CHUNK + i * 16 + lm) * D32
                                    + quad * 8);
    #pragma unroll
    for (int j = 0; j < 4; j++)
        bK[j] = *(const bf16x8*)(Ks + ((size_t)nh * L_SEQ + c * CHUNK + j * 16 + lm) * D32
                                    + quad * 8);

    // Phase A: P[i][j] tiles; upper (j>i) zero-filled
    #pragma unroll
    for (int i = 0; i < 4; i++) {
        #pragma unroll
        for (int j = 0; j < 4; j++) {
            f32x4 p = {};
            if (j <= i) {
                p = __builtin_amdgcn_mfma_f32_16x16x32_bf16(aQ[i], bK[j], p, 0, 0, 0);
                if (j == i) {
                    #pragma unroll
                    for (int r = 0; r < 4; r++)
                        if (lm > quad * 4 + r) p[r] = 0.f;   // causal: keep l' <= l
                }
            }
            #pragma unroll
            for (int r = 0; r < 4; r++)
                P[(i * 16 + quad * 4 + r) * 72 + j * 16 + lm] = f2bf(p[r]);
        }
    }
    __syncthreads();   // single wave: orders LDS writes before reads

    // preload phase-B global frags
    bf16x8 bS[2], bV[2][2];
    #pragma unroll
    for (int nt = 0; nt < 2; nt++) {
        bS[nt] = *(const bf16x8*)(SpT + (((size_t)nh * NCHUNK + c) * 32 + nt * 16 + lm) * 32
                                      + quad * 8);
        #pragma unroll
        for (int ch = 0; ch < 2; ch++)
            bV[nt][ch] = *(const bf16x8*)(Vt + ((size_t)nh * D32 + nt * 16 + lm) * L_SEQ
                                             + c * CHUNK + ch * 32 + quad * 8);
    }

    const int n = nh >> 4, h = nh & 15;
    #pragma unroll
    for (int i = 0; i < 4; i++) {
        const int chmax = (i >> 1) + 1;   // tiles of lp needed: i<2 -> 1, else 2
        bf16x8 aP[2];
        for (int ch = 0; ch < chmax; ch++)
            aP[ch] = *(const bf16x8*)&P[(i * 16 + lm) * 72 + ch * 32 + quad * 8];
        #pragma unroll
        for (int nt = 0; nt < 2; nt++) {
            f32x4 acc = {};
            acc = __builtin_amdgcn_mfma_f32_16x16x32_bf16(aQ[i], bS[nt], acc, 0, 0, 0);
            for (int ch = 0; ch < chmax; ch++)
                acc = __builtin_amdgcn_mfma_f32_16x16x32_bf16(aP[ch], bV[nt][ch], acc, 0, 0, 0);
            #pragma unroll
            for (int r = 0; r < 4; r++) {
                int lg = c * CHUNK + i * 16 + quad * 4 + r;
                out[((size_t)n * L_SEQ + lg) * DIM + h * D32 + nt * 16 + lm] = acc[r];
            }
        }
    }
}

// ---------------------------------------------------------------------------
extern "C" void kernel_launch(void* const* d_in, const int* in_sizes, int n_in,
                              void* d_out, int out_size, void* d_ws, size_t ws_size,
                              hipStream_t stream)
{
    (void)in_sizes; (void)n_in; (void)out_size; (void)ws_size;
    const float* query = (const float*)d_in[0];
    const float* key   = (const float*)d_in[1];
    const float* Wq    = (const float*)d_in[2];
    const float* Wk    = (const float*)d_in[3];
    const float* Wv    = (const float*)d_in[4];
    float* out = (float*)d_out;

    // ws layout (bf16 shorts unless noted):
    //  [qb 4.19M][kb 4.19M][wqb 256K][wkb 256K][wvb 256K]
    //  [Qs 4.19M][Ks 4.19M][Vt 4.19M][SpT 2.10M][ckvT f32 2.10M]  ~= 56 MB
    unsigned short* bf = (unsigned short*)d_ws;
    unsigned short* qb  = bf;
    unsigned short* kb  = qb + QN;
    unsigned short* wqb = kb + QN;
    unsigned short* wkb = wqb + WN;
    unsigned short* wvb = wkb + WN;
    unsigned short* Qs  = wvb + WN;
    const size_t SZ = (size_t)NH * L_SEQ * D32;
    unsigned short* Ks  = Qs + SZ;
    unsigned short* Vt  = Ks + SZ;
    unsigned short* SpT = Vt + SZ;
    float* ckvT = (float*)(SpT + (size_t)NH * NCHUNK * 1024);

    convert_kernel<<<dim3(TOT / (256 * 8)), dim3(256), 0, stream>>>(
        query, key, Wq, Wk, Wv, qb);
    gemm3_mfma_kernel<<<dim3(256, 1, 3), dim3(256), 0, stream>>>(
        qb, kb, wqb, wkb, wvb, Qs, Ks, Vt);
    chunk_kv_mfma_kernel<<<dim3(NCHUNK, NH), dim3(64), 0, stream>>>(Ks, Vt, ckvT);
    prefix_kernel<<<dim3(4, NH), dim3(64), 0, stream>>>(ckvT, SpT);
    chunk_out_mfma_kernel<<<dim3(NCHUNK, NH), dim3(64), 0, stream>>>(Qs, Ks, Vt, SpT, out);
}

// Round 3
// 138.287 us; speedup vs baseline: 1.0237x; 1.0000x over previous
//
#include <hip/hip_runtime.h>

// Problem constants (reference: N=4, L=2048, H=16, D=32, DIM=512)
#define NB      4
#define L_SEQ   2048
#define H_HEADS 16
#define D32     32
#define DIM     512
#define NH      (NB * H_HEADS)   // 64
#define CHUNK   64
#define NCHUNK  (L_SEQ / CHUNK)  // 32

typedef __attribute__((ext_vector_type(8))) short bf16x8;
typedef __attribute__((ext_vector_type(4))) float f32x4;

// f32 -> bf16 round-to-nearest-even (inputs are finite normals)
__device__ __forceinline__ unsigned short f2bf(float x) {
    unsigned u = __float_as_uint(x);
    u += 0x7fff + ((u >> 16) & 1);
    return (unsigned short)(u >> 16);
}
__device__ __forceinline__ unsigned pack2(float lo, float hi) {
    return (unsigned)f2bf(lo) | ((unsigned)f2bf(hi) << 16);
}
__device__ __forceinline__ uint4 pack8(float4 a, float4 b) {
    return make_uint4(pack2(a.x, a.y), pack2(a.z, a.w),
                      pack2(b.x, b.y), pack2(b.z, b.w));
}

// ---------------------------------------------------------------------------
// Kernel 0: f32 -> bf16 conversion of WEIGHTS ONLY (Wq, Wk, Wv) into one
// contiguous bf16 region. query/key are now converted inside gemm3's staging
// (saves the 50 MB activation round trip). 8 elements/thread, exact cover.
// ---------------------------------------------------------------------------
#define QN  4194304           // query elems (used for ws layout sizing)
#define WN  262144            // one weight matrix
#define WTOT (3*WN)           // 786,432 -> 384 blocks
__global__ __launch_bounds__(256) void convert_kernel(
    const float* __restrict__ Wq, const float* __restrict__ Wk,
    const float* __restrict__ Wv, unsigned short* __restrict__ dst)
{
    int idx = (blockIdx.x * 256 + threadIdx.x) * 8;
    const float* src; int off;
    if (idx < WN)          { src = Wq; off = idx; }
    else if (idx < 2*WN)   { src = Wk; off = idx - WN; }
    else                   { src = Wv; off = idx - 2*WN; }
    float4 a = *(const float4*)(src + off);
    float4 b = *(const float4*)(src + off + 4);
    *(uint4*)(dst + idx) = pack8(a, b);
}

// ---------------------------------------------------------------------------
// Kernel 1: three GEMMs via bf16 MFMA, fused over blockIdx.z.
//   z=0: C[l][dout] = query @ Wq^T -> softmax(heads) -> Qs [nh][l][d]
//   z=1: C[l][dout] = key   @ Wk^T -> softmax(heads) -> Ks [nh][l][d]
//   z=2: C[dout][l] = Wv @ key^T   -> Vt [nh][d][l]   (transposed compute)
//
// Round 3: fused f32->bf16 staging (T14 split). Each z has ONE f32
// activation operand (query/key) and ONE bf16 weight operand. The f32 side
// is reg-staged: float4 loads issued at step t (for buf t+2), pack+ds_write
// at step t+1, consumed at t+2 — swizzled LDS dest, LINEAR global reads.
// The bf16 side keeps global_load_lds (linear LDS dest, pre-swizzled src).
// Counted vmcnt with the mixed queue (per step: 4 f32 loads then 2 GLL):
//   mid-step  vmcnt(6): drains L_{t+1} (4 loads) before its ds_write
//   end-step  vmcnt(6): drains G_{t+1} (2 GLL) before the barrier
// Never vmcnt(0) in the main loop. LDS content layout identical to round 2,
// so frag reads / swizzle / softmax / epilogue are unchanged.
// ---------------------------------------------------------------------------
#define GLL(g, l) __builtin_amdgcn_global_load_lds( \
    (const __attribute__((address_space(1))) unsigned int*)(g), \
    (__attribute__((address_space(3))) unsigned int*)(l), 16, 0, 0)

__global__ __launch_bounds__(256) void gemm3_mfma_kernel(
    const float* __restrict__ query, const float* __restrict__ key,
    const unsigned short* __restrict__ wqb, const unsigned short* __restrict__ wkb,
    const unsigned short* __restrict__ wvb,
    unsigned short* __restrict__ Qs, unsigned short* __restrict__ Ks,
    unsigned short* __restrict__ Vt)
{
    const int z  = blockIdx.z;
    const int bx = blockIdx.x >> 6;      // 0..3  (128-col tile)
    const int by = blockIdx.x & 63;      // 0..63 (128-row tile)
    int m0, n0;
    if (z < 2) { m0 = by * 128; n0 = bx * 128; }
    else       { m0 = bx * 128; n0 = by * 128; }

    // f32 operand: z0=query(A), z1=key(A), z2=key(B). bf16 operand: weights.
    const float* fsrc = (z == 0) ? query : key;
    const unsigned short* bsrc = (z == 0) ? wqb : (z == 1) ? wkb : wvb;
    const int frb = (z < 2) ? m0 : n0;   // f32-operand row base
    const int brb = (z < 2) ? n0 : m0;   // bf16-operand row base

    __shared__ unsigned short Asm[3 * 4096];   // 3 x 8 KB (128x32 bf16)
    __shared__ unsigned short Bsm[3 * 4096];   // 3 x 8 KB
    unsigned short* fl = (z < 2) ? Asm : Bsm;  // f32-staged operand's LDS
    unsigned short* bl = (z < 2) ? Bsm : Asm;  // GLL operand's LDS

    const int t    = threadIdx.x;
    const int w    = t >> 6;
    const int lane = t & 63;
    const int wm   = w >> 1, wn = w & 1;
    const int lm   = lane & 15, quad = lane >> 4;

    // ds_read side of the involution swizzle (unchanged from round 2)
    const int qswz = quad ^ ((lm >> 1) & 3);
    const int aoff = (wm * 64 + lm) * 32 + qswz * 8;   // + i*512 per tile
    const int boff = (wn * 64 + lm) * 32 + qswz * 8;   // + j*512 per tile

    // Staging geometry: chunk li covers LDS bytes [li*16, li*16+16).
    //   f32 side: LINEAR global read (row, q), SWIZZLED ds_write dest
    //   bf16 side: pre-swizzled global src, LINEAR GLL dest
    //   swizzle: LDS[row][q ^ ((row>>1)&3)] = global[row][q]
    const int li0 = t, li1 = t + 256;
    const int row0 = li0 >> 2, q0 = li0 & 3;
    const int row1 = li1 >> 2, q1 = li1 & 3;
    const int sw0 = (row0 >> 1) & 3, sw1 = (row1 >> 1) & 3;
    const float* f0 = fsrc + (size_t)(frb + row0) * DIM + q0 * 8;
    const float* f1 = fsrc + (size_t)(frb + row1) * DIM + q1 * 8;
    const int fd0 = (row0 * 4 + (q0 ^ sw0)) * 8;   // shorts offset in LDS
    const int fd1 = (row1 * 4 + (q1 ^ sw1)) * 8;
    const unsigned short* g0 = bsrc + (size_t)(brb + row0) * DIM + (q0 ^ sw0) * 8;
    const unsigned short* g1 = bsrc + (size_t)(brb + row1) * DIM + (q1 ^ sw1) * 8;

    f32x4 acc[4][4] = {};
    float4 Pa0[2], Pa1[2], Pb0[2], Pb1[2];   // in-flight f32 stage, 2 sets

#define FLOAD(s, kb) do { \
    Pa0[s] = *(const float4*)(f0 + (kb));     Pa1[s] = *(const float4*)(f0 + (kb) + 4); \
    Pb0[s] = *(const float4*)(f1 + (kb));     Pb1[s] = *(const float4*)(f1 + (kb) + 4); \
} while (0)
#define FWRITE(s, buf) do { \
    *(uint4*)(fl + (buf) * 4096 + fd0) = pack8(Pa0[s], Pa1[s]); \
    *(uint4*)(fl + (buf) * 4096 + fd1) = pack8(Pb0[s], Pb1[s]); \
} while (0)
#define GSTAGE(buf, kb) do { \
    GLL(g0 + (kb), bl + (buf) * 4096 + li0 * 8); \
    GLL(g1 + (kb), bl + (buf) * 4096 + li1 * 8); \
} while (0)

    // prologue: queue (oldest->newest) = L0(4) G0(2) L1(4) G1(2)
    FLOAD(0, 0);
    GSTAGE(0, 0);
    FLOAD(1, 32);
    GSTAGE(1, 32);
    __builtin_amdgcn_sched_barrier(0);
    asm volatile("s_waitcnt vmcnt(8)" ::: "memory");   // drain L0
    FWRITE(0, 0);
    __builtin_amdgcn_sched_barrier(0);
    asm volatile("s_waitcnt vmcnt(6)" ::: "memory");   // drain G0
    asm volatile("s_waitcnt lgkmcnt(0)" ::: "memory"); // FWRITE landed
    __builtin_amdgcn_s_barrier();                      // buf0 ready
    __builtin_amdgcn_sched_barrier(0);

    #pragma unroll
    for (int step = 0; step < 16; ++step) {
        const int cur = step % 3;
        // (a) issue f32 loads for buf t+2 into the free register set
        if (step < 14) FLOAD(step & 1, (step + 2) * 32);
        __builtin_amdgcn_sched_barrier(0);
        // (b) drain L_{t+1}; write it into buf t+1
        if (step < 14)       asm volatile("s_waitcnt vmcnt(6)" ::: "memory");
        else if (step == 14) asm volatile("s_waitcnt vmcnt(2)" ::: "memory");
        if (step < 15) FWRITE((step + 1) & 1, (step + 1) % 3);
        __builtin_amdgcn_sched_barrier(0);
        // (c) issue GLL for buf t+2
        if (step < 14) GSTAGE((step + 2) % 3, (step + 2) * 32);
        __builtin_amdgcn_sched_barrier(0);
        // (d) compute buf t
        {
            const unsigned short* As = Asm + cur * 4096;
            const unsigned short* Bs = Bsm + cur * 4096;
            bf16x8 af[4], bfr[4];
            #pragma unroll
            for (int i = 0; i < 4; i++)
                af[i] = *(const bf16x8*)(As + aoff + i * 512);
            #pragma unroll
            for (int j = 0; j < 4; j++)
                bfr[j] = *(const bf16x8*)(Bs + boff + j * 512);
            #pragma unroll
            for (int i = 0; i < 4; i++)
                #pragma unroll
                for (int j = 0; j < 4; j++)
                    acc[i][j] = __builtin_amdgcn_mfma_f32_16x16x32_bf16(
                        af[i], bfr[j], acc[i][j], 0, 0, 0);
        }
        __builtin_amdgcn_sched_barrier(0);
        // (e) drain G_{t+1}; publish; barrier
        if (step < 14)       asm volatile("s_waitcnt vmcnt(6)" ::: "memory");
        else if (step == 14) asm volatile("s_waitcnt vmcnt(0)" ::: "memory");
        if (step < 15) {
            asm volatile("s_waitcnt lgkmcnt(0)" ::: "memory");
            __builtin_amdgcn_s_barrier();
            __builtin_amdgcn_sched_barrier(0);
        }
    }
#undef FLOAD
#undef FWRITE
#undef GSTAGE

    // fused softmax over D=32 head groups along cols (Q and K only)
    if (z < 2) {
        #pragma unroll
        for (int i = 0; i < 4; i++)
            #pragma unroll
            for (int jp = 0; jp < 2; jp++)
                #pragma unroll
                for (int r = 0; r < 4; r++) {
                    float a = acc[i][2 * jp][r], b = acc[i][2 * jp + 1][r];
                    float m = fmaxf(a, b);
                    #pragma unroll
                    for (int off = 1; off < 16; off <<= 1)
                        m = fmaxf(m, __shfl_xor(m, off, 64));
                    float ea = __expf(a - m), eb = __expf(b - m);
                    float s = ea + eb;
                    #pragma unroll
                    for (int off = 1; off < 16; off <<= 1)
                        s += __shfl_xor(s, off, 64);
                    float inv = 1.0f / s;
                    acc[i][2 * jp][r]     = ea * inv;
                    acc[i][2 * jp + 1][r] = eb * inv;
                }
    }

    // epilogue: C frag row = m0+wm*64+i*16+quad*4+r, col = n0+wn*64+j*16+lm
    #pragma unroll
    for (int i = 0; i < 4; i++) {
        int rbase = m0 + wm * 64 + i * 16 + quad * 4;
        #pragma unroll
        for (int r = 0; r < 4; r++) {
            int rg = rbase + r;
            #pragma unroll
            for (int j = 0; j < 4; j++) {
                int cg = n0 + wn * 64 + j * 16 + lm;
                unsigned short val = f2bf(acc[i][j][r]);
                if (z < 2) {
                    int n = rg >> 11, l = rg & 2047;
                    int h = cg >> 5,  e = cg & 31;
                    unsigned short* dp = (z == 0) ? Qs : Ks;
                    dp[(((size_t)(n * H_HEADS + h)) * L_SEQ + l) * D32 + e] = val;
                } else {
                    int h = rg >> 5,  e = rg & 31;     // rows are dout
                    int n = cg >> 11, l = cg & 2047;   // cols are l
                    Vt[(((size_t)(n * H_HEADS + h)) * D32 + e) * L_SEQ + l] = val;
                }
            }
        }
    }
}

// ---------------------------------------------------------------------------
// Kernel 2: per-chunk KV sums via MFMA — ONE WAVE PER CHUNK (64-thr blocks).
//   ckvT[e][d] = sum_l V[l][e] * K[l][d]
// Wave stages its chunk's K into a private LDS transpose buffer (stride 36),
// then 8 MFMAs. No inter-wave coupling; 2048 blocks.
// ---------------------------------------------------------------------------
__global__ __launch_bounds__(64) void chunk_kv_mfma_kernel(
    const unsigned short* __restrict__ Ks, const unsigned short* __restrict__ Vt,
    float* __restrict__ ckvT)
{
    const int c = blockIdx.x, nh = blockIdx.y;
    const int lane = threadIdx.x;
    const int lm = lane & 15, quad = lane >> 4;

    __shared__ unsigned short Kl[64 * 36];   // 4.5 KB

    // stage: lane loads its row (64B contiguous) -> padded LDS row
    {
        const unsigned short* kg = Ks + ((size_t)nh * L_SEQ + c * CHUNK + lane) * D32;
        #pragma unroll
        for (int i = 0; i < 4; i++) {
            uint4 v = *(const uint4*)(kg + i * 8);
            *(uint4*)(Kl + lane * 36 + i * 8) = v;
        }
    }
    __syncthreads();   // single wave: cheap; orders LDS writes before reads

    f32x4 acc[2][2] = {};
    #pragma unroll
    for (int ch = 0; ch < 2; ch++) {
        bf16x8 aV[2], bK[2];
        #pragma unroll
        for (int mt = 0; mt < 2; mt++)
            aV[mt] = *(const bf16x8*)(Vt + ((size_t)nh * D32 + mt * 16 + lm) * L_SEQ
                                         + c * CHUNK + ch * 32 + quad * 8);
        #pragma unroll
        for (int nt = 0; nt < 2; nt++) {
            const unsigned short* kp = Kl + (ch * 32 + quad * 8) * 36 + nt * 16 + lm;
            #pragma unroll
            for (int j = 0; j < 8; j++) bK[nt][j] = (short)kp[j * 36];
        }
        #pragma unroll
        for (int mt = 0; mt < 2; mt++)
            #pragma unroll
            for (int nt = 0; nt < 2; nt++)
                acc[mt][nt] = __builtin_amdgcn_mfma_f32_16x16x32_bf16(
                    aV[mt], bK[nt], acc[mt][nt], 0, 0, 0);
    }
    #pragma unroll
    for (int mt = 0; mt < 2; mt++)
        #pragma unroll
        for (int nt = 0; nt < 2; nt++)
            #pragma unroll
            for (int r = 0; r < 4; r++) {
                int e = mt * 16 + quad * 4 + r;
                int d = nt * 16 + lm;
                ckvT[(((size_t)nh * NCHUNK + c) * 32 + e) * 32 + d] = acc[mt][nt][r];
            }
}

// ---------------------------------------------------------------------------
// Kernel 3: exclusive prefix over 32 chunks; reads ckvT f32, writes SpT bf16.
// Grid (4, NH), 64 threads: block handles 64 of the 256 float4 slots.
// ---------------------------------------------------------------------------
__global__ __launch_bounds__(64) void prefix_kernel(
    const float* __restrict__ ckvT, unsigned short* __restrict__ SpT)
{
    int nh   = blockIdx.y;
    int slot = blockIdx.x * 64 + threadIdx.x;   // 0..255
    const float* base = ckvT + (size_t)nh * NCHUNK * 1024 + slot * 4;
    unsigned short* sp = SpT + (size_t)nh * NCHUNK * 1024 + slot * 4;
    float4 acc = make_float4(0.f, 0.f, 0.f, 0.f);
    #pragma unroll
    for (int cb = 0; cb < NCHUNK; cb += 8) {
        float4 v[8];
        #pragma unroll
        for (int j = 0; j < 8; j++)
            v[j] = *(const float4*)(base + (size_t)(cb + j) * 1024);
        #pragma unroll
        for (int j = 0; j < 8; j++) {
            ushort4 u;
            u.x = f2bf(acc.x); u.y = f2bf(acc.y);
            u.z = f2bf(acc.z); u.w = f2bf(acc.w);
            *(ushort4*)(sp + (size_t)(cb + j) * 1024) = u;
            acc.x += v[j].x; acc.y += v[j].y;
            acc.z += v[j].z; acc.w += v[j].w;
        }
    }
}

// ---------------------------------------------------------------------------
// Kernel 4: per-chunk output via MFMA — ONE WAVE PER CHUNK (64-thr blocks).
//   P = tril(Qc Kc^T) (bf16, private LDS);  O = Qc·SpT^T + P·Vt^T
// Wave owns all 4 row-tiles: 10 + 20 MFMAs, ~14 vector frag loads -> high ILP.
// ---------------------------------------------------------------------------
__global__ __launch_bounds__(64) void chunk_out_mfma_kernel(
    const unsigned short* __restrict__ Qs, const unsigned short* __restrict__ Ks,
    const unsigned short* __restrict__ Vt, const unsigned short* __restrict__ SpT,
    float* __restrict__ out)
{
    const int c = blockIdx.x, nh = blockIdx.y;
    __shared__ unsigned short P[64 * 72];   // row l, col l', stride 72 (9 KB)

    const int lane = threadIdx.x;
    const int lm = lane & 15, quad = lane >> 4;

    // A-frags of Q and B-frags of K for all 4 tiles
    bf16x8 aQ[4], bK[4];
    #pragma unroll
    for (int i = 0; i < 4; i++)
        aQ[i] = *(const bf16x8*)(Qs + ((size_t)nh * L_SEQ + c * CHUNK + i * 16 + lm) * D32
                                    + quad * 8);
    #pragma unroll
    for (int j = 0; j < 4; j++)
        bK[j] = *(const bf16x8*)(Ks + ((size_t)nh * L_SEQ + c * CHUNK + j * 16 + lm) * D32
                                    + quad * 8);

    // Phase A: P[i][j] tiles; upper (j>i) zero-filled
    #pragma unroll
    for (int i = 0; i < 4; i++) {
        #pragma unroll
        for (int j = 0; j < 4; j++) {
            f32x4 p = {};
            if (j <= i) {
                p = __builtin_amdgcn_mfma_f32_16x16x32_bf16(aQ[i], bK[j], p, 0, 0, 0);
                if (j == i) {
                    #pragma unroll
                    for (int r = 0; r < 4; r++)
                        if (lm > quad * 4 + r) p[r] = 0.f;   // causal: keep l' <= l
                }
            }
            #pragma unroll
            for (int r = 0; r < 4; r++)
                P[(i * 16 + quad * 4 + r) * 72 + j * 16 + lm] = f2bf(p[r]);
        }
    }
    __syncthreads();   // single wave: orders LDS writes before reads

    // preload phase-B global frags
    bf16x8 bS[2], bV[2][2];
    #pragma unroll
    for (int nt = 0; nt < 2; nt++) {
        bS[nt] = *(const bf16x8*)(SpT + (((size_t)nh * NCHUNK + c) * 32 + nt * 16 + lm) * 32
                                      + quad * 8);
        #pragma unroll
        for (int ch = 0; ch < 2; ch++)
            bV[nt][ch] = *(const bf16x8*)(Vt + ((size_t)nh * D32 + nt * 16 + lm) * L_SEQ
                                             + c * CHUNK + ch * 32 + quad * 8);
    }

    const int n = nh >> 4, h = nh & 15;
    #pragma unroll
    for (int i = 0; i < 4; i++) {
        const int chmax = (i >> 1) + 1;   // tiles of lp needed: i<2 -> 1, else 2
        bf16x8 aP[2];
        for (int ch = 0; ch < chmax; ch++)
            aP[ch] = *(const bf16x8*)&P[(i * 16 + lm) * 72 + ch * 32 + quad * 8];
        #pragma unroll
        for (int nt = 0; nt < 2; nt++) {
            f32x4 acc = {};
            acc = __builtin_amdgcn_mfma_f32_16x16x32_bf16(aQ[i], bS[nt], acc, 0, 0, 0);
            for (int ch = 0; ch < chmax; ch++)
                acc = __builtin_amdgcn_mfma_f32_16x16x32_bf16(aP[ch], bV[nt][ch], acc, 0, 0, 0);
            #pragma unroll
            for (int r = 0; r < 4; r++) {
                int lg = c * CHUNK + i * 16 + quad * 4 + r;
                out[((size_t)n * L_SEQ + lg) * DIM + h * D32 + nt * 16 + lm] = acc[r];
            }
        }
    }
}

// ---------------------------------------------------------------------------
extern "C" void kernel_launch(void* const* d_in, const int* in_sizes, int n_in,
                              void* d_out, int out_size, void* d_ws, size_t ws_size,
                              hipStream_t stream)
{
    (void)in_sizes; (void)n_in; (void)out_size; (void)ws_size;
    const float* query = (const float*)d_in[0];
    const float* key   = (const float*)d_in[1];
    const float* Wq    = (const float*)d_in[2];
    const float* Wk    = (const float*)d_in[3];
    const float* Wv    = (const float*)d_in[4];
    float* out = (float*)d_out;

    // ws layout (bf16 shorts unless noted):
    //  [wqb 256K][wkb 256K][wvb 256K]
    //  [Qs 4.19M][Ks 4.19M][Vt 4.19M][SpT 2.10M][ckvT f32 2.10M]  ~= 40 MB
    unsigned short* bf = (unsigned short*)d_ws;
    unsigned short* wqb = bf;
    unsigned short* wkb = wqb + WN;
    unsigned short* wvb = wkb + WN;
    unsigned short* Qs  = wvb + WN;
    const size_t SZ = (size_t)NH * L_SEQ * D32;
    unsigned short* Ks  = Qs + SZ;
    unsigned short* Vt  = Ks + SZ;
    unsigned short* SpT = Vt + SZ;
    float* ckvT = (float*)(SpT + (size_t)NH * NCHUNK * 1024);

    convert_kernel<<<dim3(WTOT / (256 * 8)), dim3(256), 0, stream>>>(
        Wq, Wk, Wv, wqb);
    gemm3_mfma_kernel<<<dim3(256, 1, 3), dim3(256), 0, stream>>>(
        query, key, wqb, wkb, wvb, Qs, Ks, Vt);
    chunk_kv_mfma_kernel<<<dim3(NCHUNK, NH), dim3(64), 0, stream>>>(Ks, Vt, ckvT);
    prefix_kernel<<<dim3(4, NH), dim3(64), 0, stream>>>(ckvT, SpT);
    chunk_out_mfma_kernel<<<dim3(NCHUNK, NH), dim3(64), 0, stream>>>(Qs, Ks, Vt, SpT, out);
}

// Round 4
// 133.428 us; speedup vs baseline: 1.0609x; 1.0364x over previous
//
#include <hip/hip_runtime.h>

// Problem constants (reference: N=4, L=2048, H=16, D=32, DIM=512)
#define NB      4
#define L_SEQ   2048
#define H_HEADS 16
#define D32     32
#define DIM     512
#define NH      (NB * H_HEADS)   // 64
#define CHUNK   64
#define NCHUNK  (L_SEQ / CHUNK)  // 32

typedef __attribute__((ext_vector_type(8))) short bf16x8;
typedef __attribute__((ext_vector_type(4))) float f32x4;

// f32 -> bf16 round-to-nearest-even (inputs are finite normals)
__device__ __forceinline__ unsigned short f2bf(float x) {
    unsigned u = __float_as_uint(x);
    u += 0x7fff + ((u >> 16) & 1);
    return (unsigned short)(u >> 16);
}
__device__ __forceinline__ unsigned pack2(float lo, float hi) {
    return (unsigned)f2bf(lo) | ((unsigned)f2bf(hi) << 16);
}

// ---------------------------------------------------------------------------
// Kernel 0: f32 -> bf16 conversion of query, key, Wq, Wk, Wv into one
// contiguous bf16 region (same order). 8 elements/thread, exact cover.
// (Round-4: restored — round-3's fused f32 staging was a wash; the proven
//  bf16 GLL path in gemm3 needs bf16 activations.)
// ---------------------------------------------------------------------------
#define QN  4194304           // query elems
#define WN  262144            // one weight matrix
#define TOT (2*QN + 3*WN)     // 9,175,040
__global__ __launch_bounds__(256) void convert_kernel(
    const float* __restrict__ query, const float* __restrict__ key,
    const float* __restrict__ Wq, const float* __restrict__ Wk,
    const float* __restrict__ Wv, unsigned short* __restrict__ dst)
{
    int idx = (blockIdx.x * 256 + threadIdx.x) * 8;
    const float* src; int off;
    if (idx < QN)               { src = query; off = idx; }
    else if (idx < 2*QN)        { src = key;   off = idx - QN; }
    else if (idx < 2*QN + WN)   { src = Wq;    off = idx - 2*QN; }
    else if (idx < 2*QN + 2*WN) { src = Wk;    off = idx - 2*QN - WN; }
    else                        { src = Wv;    off = idx - 2*QN - 2*WN; }
    float4 a = *(const float4*)(src + off);
    float4 b = *(const float4*)(src + off + 4);
    *(uint4*)(dst + idx) = make_uint4(pack2(a.x, a.y), pack2(a.z, a.w),
                                      pack2(b.x, b.y), pack2(b.z, b.w));
}

// ---------------------------------------------------------------------------
// Shared epilogue helpers for gemm3
// ---------------------------------------------------------------------------
__device__ __forceinline__ void softmax_heads(f32x4 (&acc)[4][4]) {
    #pragma unroll
    for (int i = 0; i < 4; i++)
        #pragma unroll
        for (int jp = 0; jp < 2; jp++)
            #pragma unroll
            for (int r = 0; r < 4; r++) {
                float a = acc[i][2 * jp][r], b = acc[i][2 * jp + 1][r];
                float m = fmaxf(a, b);
                #pragma unroll
                for (int off = 1; off < 16; off <<= 1)
                    m = fmaxf(m, __shfl_xor(m, off, 64));
                float ea = __expf(a - m), eb = __expf(b - m);
                float s = ea + eb;
                #pragma unroll
                for (int off = 1; off < 16; off <<= 1)
                    s += __shfl_xor(s, off, 64);
                float inv = 1.0f / s;
                acc[i][2 * jp][r]     = ea * inv;
                acc[i][2 * jp + 1][r] = eb * inv;
            }
}

// C frag row = m0+wm*64+i*16+quad*4+r (global l), col = n0+wn*64+j*16+lm
// (dout). Writes dp[nh][l][e] (nh = n*16+h, h=dout>>5, e=dout&31).
__device__ __forceinline__ void scatter_qk(
    const f32x4 (&acc)[4][4], unsigned short* __restrict__ dp,
    int m0, int n0, int wm, int wn, int quad, int lm)
{
    #pragma unroll
    for (int i = 0; i < 4; i++) {
        int rbase = m0 + wm * 64 + i * 16 + quad * 4;
        #pragma unroll
        for (int r = 0; r < 4; r++) {
            int rg = rbase + r;
            int n = rg >> 11, l = rg & 2047;
            #pragma unroll
            for (int j = 0; j < 4; j++) {
                int cg = n0 + wn * 64 + j * 16 + lm;
                int h = cg >> 5, e = cg & 31;
                dp[(((size_t)(n * H_HEADS + h)) * L_SEQ + l) * D32 + e] =
                    f2bf(acc[i][j][r]);
            }
        }
    }
}

// ---------------------------------------------------------------------------
// Kernel 1: projections via bf16 MFMA. Grid (256,1,2):
//   z=0: C  = query @ Wq^T -> softmax(heads) -> Qs [nh][l][d]        (16 MFMA/step)
//   z=1: C1 = key @ Wk^T -> softmax -> Ks;  C2 = key @ Wv^T -> Vt    (32 MFMA/step)
// Round 4: z1/z2 FUSION. Old z2 re-staged the same key tile z1 staged; the
// fused block stages key once (A) against BOTH Wk (B1) and Wv (B2), cutting
// total blocks 768->512 (one generation, 2 blocks/CU at 72 KB LDS) and total
// barrier-step-latencies by 1/3. C2 = (Wv@key^T)^T elementwise-identically,
// written to Vt via ushort4 row-packed stores (r=0..3 are consecutive l).
// Pipeline per branch: distance-2, 3 LDS buffers, counted vmcnt (r2-proven):
// z0 stages 4 GLL/step -> vmcnt(4); zf stages 6 GLL/step -> vmcnt(6).
// ---------------------------------------------------------------------------
#define GLL(g, l) __builtin_amdgcn_global_load_lds( \
    (const __attribute__((address_space(1))) unsigned int*)(g), \
    (__attribute__((address_space(3))) unsigned int*)(l), 16, 0, 0)

__global__ __launch_bounds__(256, 2) void gemm3_mfma_kernel(
    const unsigned short* __restrict__ qb, const unsigned short* __restrict__ kb2,
    const unsigned short* __restrict__ wqb, const unsigned short* __restrict__ wkb,
    const unsigned short* __restrict__ wvb,
    unsigned short* __restrict__ Qs, unsigned short* __restrict__ Ks,
    unsigned short* __restrict__ Vt)
{
    const int z  = blockIdx.z;           // 0: query; 1: fused key
    const int bx = blockIdx.x >> 6;      // 0..3  (128-col tile)
    const int by = blockIdx.x & 63;      // 0..63 (128-row tile); XCD swizzle:
    const int m0 = by * 128, n0 = bx * 128;  // A-sharers are 64 apart -> same XCD

    const unsigned short* PA  = z ? kb2 : qb;
    const unsigned short* PB1 = z ? wkb : wqb;

    __shared__ unsigned short Asm[3 * 4096];    // 24 KB (3 x 128x32 bf16)
    __shared__ unsigned short B1sm[3 * 4096];   // 24 KB
    __shared__ unsigned short B2sm[3 * 4096];   // 24 KB (zf only)

    const int t    = threadIdx.x;
    const int w    = t >> 6;
    const int lane = t & 63;
    const int wm   = w >> 1, wn = w & 1;
    const int lm   = lane & 15, quad = lane >> 4;

    // ds_read side of the involution swizzle (r1-proven, 0 bank conflicts)
    const int qswz = quad ^ ((lm >> 1) & 3);
    const int aoff = (wm * 64 + lm) * 32 + qswz * 8;   // + i*512 per tile
    const int boff = (wn * 64 + lm) * 32 + qswz * 8;   // + j*512 per tile

    // Staging: chunk li covers LDS bytes [li*16, li*16+16). Linear LDS dest;
    // swizzle applied by permuting the global 16B block each lane fetches:
    //   row = li>>2, q_src = (li&3) ^ ((li>>3)&3)   (involution)
    const int li0 = t, li1 = t + 256;
    const int row0 = li0 >> 2, row1 = li1 >> 2;
    const int qs0 = (li0 & 3) ^ ((li0 >> 3) & 3);
    const int qs1 = (li1 & 3) ^ ((li1 >> 3) & 3);
    const unsigned short* gA0 = PA  + (size_t)(m0 + row0) * DIM + qs0 * 8;
    const unsigned short* gA1 = PA  + (size_t)(m0 + row1) * DIM + qs1 * 8;
    const unsigned short* gB10 = PB1 + (size_t)(n0 + row0) * DIM + qs0 * 8;
    const unsigned short* gB11 = PB1 + (size_t)(n0 + row1) * DIM + qs1 * 8;

    if (z == 0) {
        // ---------------- z0: query @ Wq^T (r2-proven loop) ----------------
        f32x4 acc[4][4] = {};
#define STG0(buf, kb) do { \
        GLL(gA0  + (kb), Asm  + (buf) * 4096 + li0 * 8); \
        GLL(gB10 + (kb), B1sm + (buf) * 4096 + li0 * 8); \
        GLL(gA1  + (kb), Asm  + (buf) * 4096 + li1 * 8); \
        GLL(gB11 + (kb), B1sm + (buf) * 4096 + li1 * 8); \
} while (0)
        STG0(0, 0);
        STG0(1, 32);
        __builtin_amdgcn_sched_barrier(0);
        asm volatile("s_waitcnt vmcnt(4)" ::: "memory");
        __builtin_amdgcn_s_barrier();
        __builtin_amdgcn_sched_barrier(0);

        #pragma unroll
        for (int step = 0; step < 16; ++step) {
            const int cur = step % 3;
            if (step < 14) STG0((step + 2) % 3, (step + 2) * 32);
            const unsigned short* As = Asm + cur * 4096;
            const unsigned short* Bs = B1sm + cur * 4096;
            bf16x8 af[4], bf1[4];
            #pragma unroll
            for (int i = 0; i < 4; i++)
                af[i] = *(const bf16x8*)(As + aoff + i * 512);
            #pragma unroll
            for (int j = 0; j < 4; j++)
                bf1[j] = *(const bf16x8*)(Bs + boff + j * 512);
            #pragma unroll
            for (int i = 0; i < 4; i++)
                #pragma unroll
                for (int j = 0; j < 4; j++)
                    acc[i][j] = __builtin_amdgcn_mfma_f32_16x16x32_bf16(
                        af[i], bf1[j], acc[i][j], 0, 0, 0);
            __builtin_amdgcn_sched_barrier(0);
            if (step < 14)       asm volatile("s_waitcnt vmcnt(4)" ::: "memory");
            else if (step == 14) asm volatile("s_waitcnt vmcnt(0)" ::: "memory");
            if (step < 15) {
                __builtin_amdgcn_s_barrier();
                __builtin_amdgcn_sched_barrier(0);
            }
        }
#undef STG0
        softmax_heads(acc);
        scatter_qk(acc, Qs, m0, n0, wm, wn, quad, lm);
    } else {
        // ---------- zf: key @ {Wk^T, Wv^T} fused (32 MFMA/step) ----------
        const unsigned short* gB20 = wvb + (size_t)(n0 + row0) * DIM + qs0 * 8;
        const unsigned short* gB21 = wvb + (size_t)(n0 + row1) * DIM + qs1 * 8;
        f32x4 acc[4][4] = {};
        f32x4 acc2[4][4] = {};
#define STG1(buf, kb) do { \
        GLL(gA0  + (kb), Asm  + (buf) * 4096 + li0 * 8); \
        GLL(gB10 + (kb), B1sm + (buf) * 4096 + li0 * 8); \
        GLL(gB20 + (kb), B2sm + (buf) * 4096 + li0 * 8); \
        GLL(gA1  + (kb), Asm  + (buf) * 4096 + li1 * 8); \
        GLL(gB11 + (kb), B1sm + (buf) * 4096 + li1 * 8); \
        GLL(gB21 + (kb), B2sm + (buf) * 4096 + li1 * 8); \
} while (0)
        STG1(0, 0);
        STG1(1, 32);
        __builtin_amdgcn_sched_barrier(0);
        asm volatile("s_waitcnt vmcnt(6)" ::: "memory");
        __builtin_amdgcn_s_barrier();
        __builtin_amdgcn_sched_barrier(0);

        #pragma unroll
        for (int step = 0; step < 16; ++step) {
            const int cur = step % 3;
            if (step < 14) STG1((step + 2) % 3, (step + 2) * 32);
            const unsigned short* As  = Asm  + cur * 4096;
            const unsigned short* B1s = B1sm + cur * 4096;
            const unsigned short* B2s = B2sm + cur * 4096;
            bf16x8 af[4], bf1[4], bf2[4];
            #pragma unroll
            for (int i = 0; i < 4; i++)
                af[i] = *(const bf16x8*)(As + aoff + i * 512);
            #pragma unroll
            for (int j = 0; j < 4; j++) {
                bf1[j] = *(const bf16x8*)(B1s + boff + j * 512);
                bf2[j] = *(const bf16x8*)(B2s + boff + j * 512);
            }
            #pragma unroll
            for (int i = 0; i < 4; i++)
                #pragma unroll
                for (int j = 0; j < 4; j++) {
                    acc[i][j]  = __builtin_amdgcn_mfma_f32_16x16x32_bf16(
                        af[i], bf1[j], acc[i][j], 0, 0, 0);
                    acc2[i][j] = __builtin_amdgcn_mfma_f32_16x16x32_bf16(
                        af[i], bf2[j], acc2[i][j], 0, 0, 0);
                }
            __builtin_amdgcn_sched_barrier(0);
            if (step < 14)       asm volatile("s_waitcnt vmcnt(6)" ::: "memory");
            else if (step == 14) asm volatile("s_waitcnt vmcnt(0)" ::: "memory");
            if (step < 15) {
                __builtin_amdgcn_s_barrier();
                __builtin_amdgcn_sched_barrier(0);
            }
        }
#undef STG1
        softmax_heads(acc);
        scatter_qk(acc, Ks, m0, n0, wm, wn, quad, lm);
        // C2 -> Vt[nh][e][l]: rows r=0..3 are consecutive l -> ushort4 packs.
        #pragma unroll
        for (int i = 0; i < 4; i++) {
            int lg0 = m0 + wm * 64 + i * 16 + quad * 4;
            int nb = lg0 >> 11, ll = lg0 & 2047;
            #pragma unroll
            for (int j = 0; j < 4; j++) {
                int cg = n0 + wn * 64 + j * 16 + lm;
                int h = cg >> 5, e = cg & 31;
                ushort4 u;
                u.x = f2bf(acc2[i][j][0]); u.y = f2bf(acc2[i][j][1]);
                u.z = f2bf(acc2[i][j][2]); u.w = f2bf(acc2[i][j][3]);
                *(ushort4*)(Vt + (((size_t)(nb * H_HEADS + h)) * D32 + e) * L_SEQ + ll) = u;
            }
        }
    }
}

// ---------------------------------------------------------------------------
// Kernel 2: per-chunk KV sums via MFMA — ONE WAVE PER CHUNK (64-thr blocks).
//   ckvT[e][d] = sum_l V[l][e] * K[l][d]
// Wave stages its chunk's K into a private LDS transpose buffer (stride 36),
// then 8 MFMAs. No inter-wave coupling; 2048 blocks.
// ---------------------------------------------------------------------------
__global__ __launch_bounds__(64) void chunk_kv_mfma_kernel(
    const unsigned short* __restrict__ Ks, const unsigned short* __restrict__ Vt,
    float* __restrict__ ckvT)
{
    const int c = blockIdx.x, nh = blockIdx.y;
    const int lane = threadIdx.x;
    const int lm = lane & 15, quad = lane >> 4;

    __shared__ unsigned short Kl[64 * 36];   // 4.5 KB

    // stage: lane loads its row (64B contiguous) -> padded LDS row
    {
        const unsigned short* kg = Ks + ((size_t)nh * L_SEQ + c * CHUNK + lane) * D32;
        #pragma unroll
        for (int i = 0; i < 4; i++) {
            uint4 v = *(const uint4*)(kg + i * 8);
            *(uint4*)(Kl + lane * 36 + i * 8) = v;
        }
    }
    __syncthreads();   // single wave: cheap; orders LDS writes before reads

    f32x4 acc[2][2] = {};
    #pragma unroll
    for (int ch = 0; ch < 2; ch++) {
        bf16x8 aV[2], bK[2];
        #pragma unroll
        for (int mt = 0; mt < 2; mt++)
            aV[mt] = *(const bf16x8*)(Vt + ((size_t)nh * D32 + mt * 16 + lm) * L_SEQ
                                         + c * CHUNK + ch * 32 + quad * 8);
        #pragma unroll
        for (int nt = 0; nt < 2; nt++) {
            const unsigned short* kp = Kl + (ch * 32 + quad * 8) * 36 + nt * 16 + lm;
            #pragma unroll
            for (int j = 0; j < 8; j++) bK[nt][j] = (short)kp[j * 36];
        }
        #pragma unroll
        for (int mt = 0; mt < 2; mt++)
            #pragma unroll
            for (int nt = 0; nt < 2; nt++)
                acc[mt][nt] = __builtin_amdgcn_mfma_f32_16x16x32_bf16(
                    aV[mt], bK[nt], acc[mt][nt], 0, 0, 0);
    }
    #pragma unroll
    for (int mt = 0; mt < 2; mt++)
        #pragma unroll
        for (int nt = 0; nt < 2; nt++)
            #pragma unroll
            for (int r = 0; r < 4; r++) {
                int e = mt * 16 + quad * 4 + r;
                int d = nt * 16 + lm;
                ckvT[(((size_t)nh * NCHUNK + c) * 32 + e) * 32 + d] = acc[mt][nt][r];
            }
}

// ---------------------------------------------------------------------------
// Kernel 3: exclusive prefix over 32 chunks; reads ckvT f32, writes SpT bf16.
// Grid (4, NH), 64 threads: block handles 64 of the 256 float4 slots.
// ---------------------------------------------------------------------------
__global__ __launch_bounds__(64) void prefix_kernel(
    const float* __restrict__ ckvT, unsigned short* __restrict__ SpT)
{
    int nh   = blockIdx.y;
    int slot = blockIdx.x * 64 + threadIdx.x;   // 0..255
    const float* base = ckvT + (size_t)nh * NCHUNK * 1024 + slot * 4;
    unsigned short* sp = SpT + (size_t)nh * NCHUNK * 1024 + slot * 4;
    float4 acc = make_float4(0.f, 0.f, 0.f, 0.f);
    #pragma unroll
    for (int cb = 0; cb < NCHUNK; cb += 8) {
        float4 v[8];
        #pragma unroll
        for (int j = 0; j < 8; j++)
            v[j] = *(const float4*)(base + (size_t)(cb + j) * 1024);
        #pragma unroll
        for (int j = 0; j < 8; j++) {
            ushort4 u;
            u.x = f2bf(acc.x); u.y = f2bf(acc.y);
            u.z = f2bf(acc.z); u.w = f2bf(acc.w);
            *(ushort4*)(sp + (size_t)(cb + j) * 1024) = u;
            acc.x += v[j].x; acc.y += v[j].y;
            acc.z += v[j].z; acc.w += v[j].w;
        }
    }
}

// ---------------------------------------------------------------------------
// Kernel 4: per-chunk output via MFMA — ONE WAVE PER CHUNK (64-thr blocks).
//   P = tril(Qc Kc^T) (bf16, private LDS);  O = Qc·SpT^T + P·Vt^T
// Wave owns all 4 row-tiles: 10 + 20 MFMAs, ~14 vector frag loads -> high ILP.
// ---------------------------------------------------------------------------
__global__ __launch_bounds__(64) void chunk_out_mfma_kernel(
    const unsigned short* __restrict__ Qs, const unsigned short* __restrict__ Ks,
    const unsigned short* __restrict__ Vt, const unsigned short* __restrict__ SpT,
    float* __restrict__ out)
{
    const int c = blockIdx.x, nh = blockIdx.y;
    __shared__ unsigned short P[64 * 72];   // row l, col l', stride 72 (9 KB)

    const int lane = threadIdx.x;
    const int lm = lane & 15, quad = lane >> 4;

    // A-frags of Q and B-frags of K for all 4 tiles
    bf16x8 aQ[4], bK[4];
    #pragma unroll
    for (int i = 0; i < 4; i++)
        aQ[i] = *(const bf16x8*)(Qs + ((size_t)nh * L_SEQ + c * CHUNK + i * 16 + lm) * D32
                                    + quad * 8);
    #pragma unroll
    for (int j = 0; j < 4; j++)
        bK[j] = *(const bf16x8*)(Ks + ((size_t)nh * L_SEQ + c * CHUNK + j * 16 + lm) * D32
                                    + quad * 8);

    // Phase A: P[i][j] tiles; upper (j>i) zero-filled
    #pragma unroll
    for (int i = 0; i < 4; i++) {
        #pragma unroll
        for (int j = 0; j < 4; j++) {
            f32x4 p = {};
            if (j <= i) {
                p = __builtin_amdgcn_mfma_f32_16x16x32_bf16(aQ[i], bK[j], p, 0, 0, 0);
                if (j == i) {
                    #pragma unroll
                    for (int r = 0; r < 4; r++)
                        if (lm > quad * 4 + r) p[r] = 0.f;   // causal: keep l' <= l
                }
            }
            #pragma unroll
            for (int r = 0; r < 4; r++)
                P[(i * 16 + quad * 4 + r) * 72 + j * 16 + lm] = f2bf(p[r]);
        }
    }
    __syncthreads();   // single wave: orders LDS writes before reads

    // preload phase-B global frags
    bf16x8 bS[2], bV[2][2];
    #pragma unroll
    for (int nt = 0; nt < 2; nt++) {
        bS[nt] = *(const bf16x8*)(SpT + (((size_t)nh * NCHUNK + c) * 32 + nt * 16 + lm) * 32
                                      + quad * 8);
        #pragma unroll
        for (int ch = 0; ch < 2; ch++)
            bV[nt][ch] = *(const bf16x8*)(Vt + ((size_t)nh * D32 + nt * 16 + lm) * L_SEQ
                                             + c * CHUNK + ch * 32 + quad * 8);
    }

    const int n = nh >> 4, h = nh & 15;
    #pragma unroll
    for (int i = 0; i < 4; i++) {
        const int chmax = (i >> 1) + 1;   // tiles of lp needed: i<2 -> 1, else 2
        bf16x8 aP[2];
        for (int ch = 0; ch < chmax; ch++)
            aP[ch] = *(const bf16x8*)&P[(i * 16 + lm) * 72 + ch * 32 + quad * 8];
        #pragma unroll
        for (int nt = 0; nt < 2; nt++) {
            f32x4 acc = {};
            acc = __builtin_amdgcn_mfma_f32_16x16x32_bf16(aQ[i], bS[nt], acc, 0, 0, 0);
            for (int ch = 0; ch < chmax; ch++)
                acc = __builtin_amdgcn_mfma_f32_16x16x32_bf16(aP[ch], bV[nt][ch], acc, 0, 0, 0);
            #pragma unroll
            for (int r = 0; r < 4; r++) {
                int lg = c * CHUNK + i * 16 + quad * 4 + r;
                out[((size_t)n * L_SEQ + lg) * DIM + h * D32 + nt * 16 + lm] = acc[r];
            }
        }
    }
}

// ---------------------------------------------------------------------------
extern "C" void kernel_launch(void* const* d_in, const int* in_sizes, int n_in,
                              void* d_out, int out_size, void* d_ws, size_t ws_size,
                              hipStream_t stream)
{
    (void)in_sizes; (void)n_in; (void)out_size; (void)ws_size;
    const float* query = (const float*)d_in[0];
    const float* key   = (const float*)d_in[1];
    const float* Wq    = (const float*)d_in[2];
    const float* Wk    = (const float*)d_in[3];
    const float* Wv    = (const float*)d_in[4];
    float* out = (float*)d_out;

    // ws layout (bf16 shorts unless noted):
    //  [qb 4.19M][kb 4.19M][wqb 256K][wkb 256K][wvb 256K]
    //  [Qs 4.19M][Ks 4.19M][Vt 4.19M][SpT 2.10M][ckvT f32 2.10M]  ~= 56 MB
    unsigned short* bf = (unsigned short*)d_ws;
    unsigned short* qb  = bf;
    unsigned short* kb  = qb + QN;
    unsigned short* wqb = kb + QN;
    unsigned short* wkb = wqb + WN;
    unsigned short* wvb = wkb + WN;
    unsigned short* Qs  = wvb + WN;
    const size_t SZ = (size_t)NH * L_SEQ * D32;
    unsigned short* Ks  = Qs + SZ;
    unsigned short* Vt  = Ks + SZ;
    unsigned short* SpT = Vt + SZ;
    float* ckvT = (float*)(SpT + (size_t)NH * NCHUNK * 1024);

    convert_kernel<<<dim3(TOT / (256 * 8)), dim3(256), 0, stream>>>(
        query, key, Wq, Wk, Wv, qb);
    gemm3_mfma_kernel<<<dim3(256, 1, 2), dim3(256), 0, stream>>>(
        qb, kb, wqb, wkb, wvb, Qs, Ks, Vt);
    chunk_kv_mfma_kernel<<<dim3(NCHUNK, NH), dim3(64), 0, stream>>>(Ks, Vt, ckvT);
    prefix_kernel<<<dim3(4, NH), dim3(64), 0, stream>>>(ckvT, SpT);
    chunk_out_mfma_kernel<<<dim3(NCHUNK, NH), dim3(64), 0, stream>>>(Qs, Ks, Vt, SpT, out);
}